// Round 9
// baseline (117.783 us; speedup 1.0000x reference)
//
#include <hip/hip_runtime.h>
#include <hip/hip_bf16.h>
#include <stdint.h>

// Problem: B=32, N=512, C=16, D=O=256.  Flattened nodes = 16384.
// nb : bf16 [16384][256]  (converted nodes; gather input + GEMM A k in [0,256))
// wsb: bf16 [slab][n][kw] (24 x 256 x 32), k = slab*32+kw;
//      k rows 0..255 = w_t, 256..511 = w_r, 512..767 = w_l.
// Fused kernel: 512 blocks x 1024 thr (2 blocks/CU = 32 waves/CU, HW max).
// Phase 1: 2 nodes/wave gather -> LDS. Phase 2: wave = 16x32 MFMA sub-tile.
#define CC 16
#define OO 256
#define NSLAB 24
#define NB_ELS (16384 * 256)
#define A2STR 520            // 512 + 8 pad (bf16 units)

typedef __attribute__((ext_vector_type(8))) short bf16x8;
typedef __attribute__((ext_vector_type(4))) float f32x4;

__device__ __forceinline__ unsigned short f2bf(float x) {
    unsigned u = __builtin_bit_cast(unsigned, x);
    u += 0x7FFFu + ((u >> 16) & 1u);
    return (unsigned short)(u >> 16);
}

// ---------------------------------------------------------------------------
// Kernel 0: prep — nodes fp32 -> bf16 (nb, XCD-swizzled rows); weights -> wsb
// ---------------------------------------------------------------------------
__global__ __launch_bounds__(256) void prep(
    const float* __restrict__ nodes, const float* __restrict__ wt,
    const float* __restrict__ wrp, const float* __restrict__ wl,
    unsigned short* __restrict__ nb, unsigned short* __restrict__ wsb) {

    __shared__ unsigned short T[256 * 40];
    const int p = blockIdx.x;
    const int tid = threadIdx.x;

    if (p < 2048) {                       // 8 rows/block; XCD x owns [x*2048,+2048)
        const int pp = (p & 7) * 256 + (p >> 3);
        const size_t t = (size_t)pp * 256 + tid;   // 8 fp32 per thread
        const float4* s = (const float4*)nodes + t * 2;
        float4 a = s[0], b = s[1];
        uint4 u;
        u.x = (unsigned)f2bf(a.x) | ((unsigned)f2bf(a.y) << 16);
        u.y = (unsigned)f2bf(a.z) | ((unsigned)f2bf(a.w) << 16);
        u.z = (unsigned)f2bf(b.x) | ((unsigned)f2bf(b.y) << 16);
        u.w = (unsigned)f2bf(b.z) | ((unsigned)f2bf(b.w) << 16);
        *(uint4*)(nb + (t >> 5) * 256 + (t & 31) * 8) = u;
        return;
    }
    // ---- weight prep: one block per K-slab, LDS transpose ----
    const int slab = p - 2048;           // 0..23
    const int n = tid;                   // 0..255
#pragma unroll
    for (int kk = 0; kk < 32; ++kk) {
        const int k = slab * 32 + kk;    // 0..255 w_t, 256..511 w_r, 512..767 w_l
        const float* s = (k < 256) ? wt : ((k < 512) ? wrp : wl);
        T[n * 40 + kk] = f2bf(s[(k & 255) * OO + n]);
    }
    __syncthreads();
    uint4* dst = (uint4*)(wsb + slab * 8192 + n * 32);
    const uint4* src = (const uint4*)&T[n * 40];
#pragma unroll
    for (int q = 0; q < 4; ++q) dst[q] = src[q];
}

// ---------------------------------------------------------------------------
// Kernel 1: fused gather + GEMM + epilogue. 512 blocks x 1024 thr.
// __launch_bounds__(1024,8): 8 waves/SIMD -> VGPR<=64 -> 2 blocks/CU resident.
// ---------------------------------------------------------------------------
__global__ __launch_bounds__(1024, 8) void tbcnn_fused(
    const int* __restrict__ children, const unsigned short* __restrict__ nb,
    const unsigned short* __restrict__ wsb, const float* __restrict__ conv,
    float* __restrict__ out) {

    __shared__ unsigned short A2[32 * A2STR];    // 33,280 B: k'=k-256 in [0,512)

    const int tid  = threadIdx.x;
    const int wave = tid >> 6;                   // 0..15
    const int lane = tid & 63;
    const int x = blockIdx.x & 7;                // XCD (dispatch round-robin)
    const int q = blockIdx.x >> 3;               // 0..63
    const int rbase = x * 2048 + q * 32;         // 32 rows, produced on XCD x

    // ---------------- Phase 1: gather -> LDS (2 nodes per wave) -------------
#pragma unroll 1
    for (int i = 0; i < 2; ++i) {
        const int m  = wave * 2 + i;             // local row 0..31
        const int nf = __builtin_amdgcn_readfirstlane(rbase + m);
        const int brow = nf & ~511;              // b*512
        const int* chp = children + (nf << 4);   // 64 B aligned -> s_load x16
        int cj[CC];
#pragma unroll
        for (int j = 0; j < CC; ++j) cj[j] = chp[j];     // scalar loads (SGPR)
        int ns = 0;
#pragma unroll
        for (int j = 0; j < CC; ++j) ns += (cj[j] != 0) ? 1 : 0;
        const float inv_den = (ns > 1) ? 1.0f / (float)(ns - 1) : 0.0f;
        const bool single = (ns == 1);

        uint2 ec[CC];                            // 16 child rows, 8 B/lane
#pragma unroll
        for (int j = 0; j < CC; ++j)
            ec[j] = *(const uint2*)(nb + (size_t)(brow + cj[j]) * 256 + lane * 4);

        float4 ar = make_float4(0.f, 0.f, 0.f, 0.f);
        float4 as = make_float4(0.f, 0.f, 0.f, 0.f);
#pragma unroll
        for (int j = 0; j < CC; ++j) {
            const float hasf = (cj[j] != 0) ? 1.0f : 0.0f;
            const float crr = single ? ((j == 0) ? 0.5f : 0.0f)
                                     : (float)j * inv_den;
            const float cr = crr * hasf;
            const float e0 = __builtin_bit_cast(float, ec[j].x << 16);
            const float e1 = __builtin_bit_cast(float, ec[j].x & 0xFFFF0000u);
            const float e2 = __builtin_bit_cast(float, ec[j].y << 16);
            const float e3 = __builtin_bit_cast(float, ec[j].y & 0xFFFF0000u);
            ar.x += cr * e0;   ar.y += cr * e1;   ar.z += cr * e2;   ar.w += cr * e3;
            as.x += hasf * e0; as.y += hasf * e1; as.z += hasf * e2; as.w += hasf * e3;
        }
        unsigned short* rowp = &A2[m * A2STR];
        uint2 v;
        v.x = (unsigned)f2bf(ar.x) | ((unsigned)f2bf(ar.y) << 16);
        v.y = (unsigned)f2bf(ar.z) | ((unsigned)f2bf(ar.w) << 16);
        *(uint2*)(rowp + lane * 4) = v;                          // k' 0..255: w_r
        v.x = (unsigned)f2bf(as.x - ar.x) | ((unsigned)f2bf(as.y - ar.y) << 16);
        v.y = (unsigned)f2bf(as.z - ar.z) | ((unsigned)f2bf(as.w - ar.w) << 16);
        *(uint2*)(rowp + 256 + lane * 4) = v;                    // k' 256..511: w_l
    }
    __syncthreads();

    // ---------------- Phase 2: MFMA K-loop. wave -> 16 rows x 32 cols -------
    const int quad = lane >> 4;
    const int l16  = lane & 15;
    const int wr   = wave >> 3;                  // M half: rows wr*16..+16
    const int wc   = wave & 7;                   // N: cols wc*32..+32
    f32x4 acc[2];
    acc[0] = (f32x4){0.f, 0.f, 0.f, 0.f};
    acc[1] = (f32x4){0.f, 0.f, 0.f, 0.f};

    // B fragment base: col = wc*32 + ni*16 + l16 (1 KB coalesced per load)
    const unsigned short* bbase = wsb + (wc * 32 + l16) * 32 + quad * 8;
    // A parent frags (slabs 0..7): nb rows rbase+wr*16+l16, k = s*32+quad*8
    const unsigned short* aG = nb + (size_t)(rbase + wr * 16 + l16) * 256 + quad * 8;
    // A LDS frags (slabs 8..23)
    const unsigned short* aL = &A2[(wr * 16 + l16) * A2STR + quad * 8];

#pragma unroll 2
    for (int s = 0; s < 8; ++s) {
        bf16x8 af = *(const bf16x8*)(aG + s * 32);
        bf16x8 b0 = *(const bf16x8*)(bbase + s * 8192);
        bf16x8 b1 = *(const bf16x8*)(bbase + s * 8192 + 512);
        acc[0] = __builtin_amdgcn_mfma_f32_16x16x32_bf16(af, b0, acc[0], 0, 0, 0);
        acc[1] = __builtin_amdgcn_mfma_f32_16x16x32_bf16(af, b1, acc[1], 0, 0, 0);
    }
#pragma unroll 2
    for (int s = 8; s < 24; ++s) {
        bf16x8 af = *(const bf16x8*)(aL + (s - 8) * 32);
        bf16x8 b0 = *(const bf16x8*)(bbase + s * 8192);
        bf16x8 b1 = *(const bf16x8*)(bbase + s * 8192 + 512);
        acc[0] = __builtin_amdgcn_mfma_f32_16x16x32_bf16(af, b0, acc[0], 0, 0, 0);
        acc[1] = __builtin_amdgcn_mfma_f32_16x16x32_bf16(af, b1, acc[1], 0, 0, 0);
    }

    // ---------------- Epilogue: + conv, leaky_relu(0.01), fp32 store --------
#pragma unroll
    for (int ni = 0; ni < 2; ++ni) {
        const int col = wc * 32 + ni * 16 + l16;
        const float cv = conv[col];
#pragma unroll
        for (int r = 0; r < 4; ++r) {
            const int row = rbase + wr * 16 + quad * 4 + r;  // C/D: row=quad*4+reg
            float v = acc[ni][r] + cv;
            v = (v > 0.f) ? v : 0.01f * v;
            out[(size_t)row * OO + col] = v;
        }
    }
}

extern "C" void kernel_launch(void* const* d_in, const int* in_sizes, int n_in,
                              void* d_out, int out_size, void* d_ws, size_t ws_size,
                              hipStream_t stream) {
    // setup_inputs order: nodes, w_t, w_l, w_r, conv, children
    const float* nodes    = (const float*)d_in[0];
    const float* w_t      = (const float*)d_in[1];
    const float* w_l      = (const float*)d_in[2];
    const float* w_r      = (const float*)d_in[3];
    const float* conv     = (const float*)d_in[4];
    const int*   children = (const int*)d_in[5];

    unsigned short* nb  = (unsigned short*)d_ws;          // 8,388,608 B
    unsigned short* wsb = nb + NB_ELS;                    // +  393,216 B

    prep<<<2048 + 24, 256, 0, stream>>>(nodes, w_t, w_r, w_l, nb, wsb);
    tbcnn_fused<<<512, 1024, 0, stream>>>(children, nb, wsb, conv, (float*)d_out);
}